// Round 1
// baseline (6774.453 us; speedup 1.0000x reference)
//
#include <hip/hip_runtime.h>
#include <hip/hip_bf16.h>
#include <stdint.h>

// GatedGNN: B=256, N=80, D=1024, T=3
#define B_   256
#define N_   80
#define D_   1024
#define M_   (B_*N_)     // 20480 rows (b*80+node)
// Abuf row (bf16), SA_=8192: [a_hi(0:2048)|a_lo(2048:4096)|h_hi(4096:5120)|h_lo(5120:6144)|rh_hi(6144:7168)|rh_lo(7168:8192)]
#define SA_  8192
// W row (bf16), SW_=6144: [w_a_hi(0:2048)|w_a_lo(2048:4096)|w_u_hi(4096:5120)|w_u_lo(5120:6144)]
#define SW_  6144
#define KT_  144         // 144 BK=64 tiles -> K_eff = 9216 (3-term split product)

typedef __attribute__((ext_vector_type(8))) short bf16x8;   // 8 bf16 = 4 VGPRs
typedef __attribute__((ext_vector_type(4))) float f32x4;

__device__ __forceinline__ void async_cp16(const void* g, void* l) {
  __builtin_amdgcn_global_load_lds((const __attribute__((address_space(1))) unsigned int*)g,
                                   (__attribute__((address_space(3))) unsigned int*)l,
                                   16, 0, 0);
}
__device__ __forceinline__ float sigm_(float x) { return 1.0f / (1.0f + __expf(-x)); }
__device__ __forceinline__ float tanh_(float x) { return 2.0f / (1.0f + __expf(-2.0f * x)) - 1.0f; }
__device__ __forceinline__ void split_bf16(float v, __hip_bfloat16& hi, __hip_bfloat16& lo) {
  hi = __float2bfloat16(v);
  lo = __float2bfloat16(v - __bfloat162float(hi));
}

// segment plan: [0,32) a_hi*w_hi  [32,64) a_lo*w_hi  [64,96) a_hi*w_lo
//               [96,112) u_hi*wu_hi [112,128) u_lo*wu_hi [128,144) u_hi*wu_lo
__device__ __forceinline__ void seg_offsets(int kt, int UBASE, int& aoffk, int& woffk) {
  if (kt < 64)       { aoffk = kt * 64;          woffk = (kt < 32) ? kt * 64 : kt * 64 - 2048; }
  else if (kt < 96)  { aoffk = kt * 64 - 4096;   woffk = kt * 64 - 2048; }
  else if (kt < 112) { int r = (kt - 96) * 64;  aoffk = UBASE + r;        woffk = 4096 + r; }
  else if (kt < 128) { int r = (kt - 112) * 64; aoffk = UBASE + 1024 + r; woffk = 4096 + r; }
  else               { int r = (kt - 128) * 64; aoffk = UBASE + r;        woffk = 5120 + r; }
}

// ---------------- weight packing (hi/lo split): Wzr[2048][SW_], Wh[1024][SW_] ------------------
__global__ __launch_bounds__(256) void pack_weights(
    const float* __restrict__ W1w, const float* __restrict__ W1u,
    const float* __restrict__ W2w, const float* __restrict__ W2u,
    const float* __restrict__ W3w, const float* __restrict__ W3u,
    __hip_bfloat16* __restrict__ Wzr, __hip_bfloat16* __restrict__ Wh) {
  int idx = blockIdx.x * 256 + threadIdx.x;     // [0, 3072*3072)
  int n = idx / 3072, k = idx - n * 3072;       // n: 0..3071 output row, k: source col
  const float *Ww, *Wu; int nr; __hip_bfloat16* outrow;
  if (n < 1024)      { Ww = W1w; Wu = W1u; nr = n;        outrow = Wzr + (size_t)n * SW_; }
  else if (n < 2048) { Ww = W2w; Wu = W2u; nr = n - 1024; outrow = Wzr + (size_t)n * SW_; }
  else               { Ww = W3w; Wu = W3u; nr = n - 2048; outrow = Wh + (size_t)(n - 2048) * SW_; }
  float v; int chi, clo;
  if (k < 2048) { v = Ww[nr * 2048 + k];          chi = k;               clo = 2048 + k; }
  else          { v = Wu[nr * 1024 + (k - 2048)]; chi = 4096 + (k-2048); clo = 5120 + (k - 2048); }
  __hip_bfloat16 hi, lo; split_bf16(v, hi, lo);
  outrow[chi] = hi; outrow[clo] = lo;
}

// ---------------- propagation: a_in/a_out = inM/outM @ h[b] (fp32), split -> Abuf --------------
__global__ __launch_bounds__(256) void prop_kernel(
    const float* __restrict__ h, const float* __restrict__ inM,
    const float* __restrict__ outM, __hip_bfloat16* __restrict__ Abuf) {
  const int b = blockIdx.x;                        // chunk-local batch index
  const int d = blockIdx.y * 256 + threadIdx.x;
  const float* hb = h + (size_t)b * N_ * D_ + d;
  float hreg[N_];
  #pragma unroll
  for (int m = 0; m < N_; ++m) hreg[m] = hb[m * D_];
  __hip_bfloat16* Ab = Abuf + (size_t)b * N_ * SA_;
  #pragma unroll
  for (int m = 0; m < N_; ++m) {
    __hip_bfloat16 hi, lo; split_bf16(hreg[m], hi, lo);
    Ab[m * SA_ + 4096 + d] = hi; Ab[m * SA_ + 5120 + d] = lo;
  }
  for (int n = 0; n < N_; ++n) {
    float ai = 0.f, ao = 0.f;
    #pragma unroll
    for (int m = 0; m < N_; ++m) {
      ai += inM[n * N_ + m] * hreg[m];
      ao += outM[n * N_ + m] * hreg[m];
    }
    __hip_bfloat16 hi, lo;
    split_bf16(ai, hi, lo); Ab[n * SA_ + d] = hi;        Ab[n * SA_ + 2048 + d] = lo;
    split_bf16(ao, hi, lo); Ab[n * SA_ + 1024 + d] = hi; Ab[n * SA_ + 3072 + d] = lo;
  }
}

// ---------------- MFMA GEMM, 160x128 tile, BK=64, 3-term split-bf16 K plan --------------------
// wave-grid 2x2, wave-tile 80m x 64n, acc 5x4 (80 AGPR).
// T3 2-phase pipeline: double-buffered LDS (72 KB, 2 blocks/CU), STAGE(k+1) issued BEFORE
// ds_read+MFMA of tile k, ONE vmcnt(0)+barrier per iteration -> load latency hides under MFMA.
// ZR: 2048 blocks / 512 resident = 4.0 exact rounds; H: 2.0 exact rounds (no tail).
#define STAGE_TILES(BUF, AOFFK, WOFFK) do {                                                   \
    _Pragma("unroll")                                                                         \
    for (int i_ = 0; i_ < 5; ++i_) {              /* A: 1280 chunks, 5 per thread */          \
      const int cidx = i_ * 256 + tid;                                                        \
      const int ks = cidx / 640;                                                              \
      const int rr = cidx - ks * 640;                                                         \
      const int q  = rr & 3;                                                                  \
      const int mm = rr >> 2;                                                                 \
      async_cp16(Abuf + (size_t)(m0 + mm) * SA_ + (AOFFK) + ks * 32 + q * 8,                  \
                 &ldsA[(BUF) * 1280 + cidx]);                                                 \
    }                                                                                         \
    _Pragma("unroll")                                                                         \
    for (int j_ = 0; j_ < 4; ++j_) {              /* B: 1024 chunks, 4 per thread */          \
      const int cidx = j_ * 256 + tid;                                                        \
      const int q  = cidx & 3;                                                                \
      const int nn = (cidx >> 2) & 127;                                                       \
      const int ks = cidx >> 9;                                                               \
      async_cp16(W + (size_t)(n0 + nn) * SW_ + (WOFFK) + ks * 32 + q * 8,                     \
                 &ldsB[(BUF) * 1024 + cidx]);                                                 \
    }                                                                                         \
  } while (0)

template<bool IS_ZR>
__global__ __launch_bounds__(256, 2) void gemm_kernel(
    const __hip_bfloat16* __restrict__ Abuf,   // [rows][SA_] chunk-local
    const __hip_bfloat16* __restrict__ W,      // [Nout][SW_]
    const float* __restrict__ bw1, const float* __restrict__ bu1,
    const float* __restrict__ bw2, const float* __restrict__ bu2,
    const float* __restrict__ hcur,            // [rows][1024] fp32, chunk-local
    float* __restrict__ zbuf,                  // [rows][1024] fp32, chunk-local
    __hip_bfloat16* __restrict__ rhbase,       // = Abuf (rh at cols 6144/7168)
    float* __restrict__ hout,
    int mtiles) {
  __shared__ bf16x8 ldsA[2560];   // 40 KB: dbuf(2) x ks(2) x 160 m-rows x 4 chunks
  __shared__ bf16x8 ldsB[2048];   // 32 KB: dbuf(2) x ks(2) x 128 n-rows x 4 chunks

  const int ntiles = IS_ZR ? 16 : 8;           // 128-wide n tiles
  int mt, nt;
  if ((mtiles & 7) == 0) {
    const int flat = blockIdx.x;
    const int strip = mtiles >> 3;             // m-tiles per XCD
    const int xcd = flat & 7;
    const int loc = flat >> 3;                 // [0, strip*ntiles)
    mt = xcd * strip + loc / ntiles;
    nt = loc - (loc / ntiles) * ntiles;
  } else {
    mt = blockIdx.x / ntiles;
    nt = blockIdx.x - mt * ntiles;
  }
  const int m0 = mt * 160;
  const int n0 = nt * 128;

  const int tid  = threadIdx.x;
  const int lane = tid & 63;
  const int wave = tid >> 6;
  const int wm   = (wave & 1) * 80;
  const int wn   = (wave >> 1) * 64;
  const int l15  = lane & 15;
  const int l4   = lane >> 4;
  const int UBASE = IS_ZR ? 4096 : 6144;   // u-operand: h for ZR, r*h for H

  f32x4 acc[5][4];
  #pragma unroll
  for (int i = 0; i < 5; ++i)
    #pragma unroll
    for (int j = 0; j < 4; ++j) acc[i][j] = (f32x4){0.f, 0.f, 0.f, 0.f};

  const int aoff = (wm + l15) * 4 + l4;
  const int boff = (wn + l15) * 4 + l4;

  // ---- prologue: stage tile 0 into buffer 0, drain, barrier ----
  int aoffk, woffk;
  seg_offsets(0, UBASE, aoffk, woffk);
  STAGE_TILES(0, aoffk, woffk);
  asm volatile("s_waitcnt vmcnt(0)" ::: "memory");
  __syncthreads();

  int cur = 0;
  for (int kt = 0; kt < KT_; ++kt) {
    // phase 1: issue next tile's global->LDS loads into the other buffer (in flight
    // across the whole ds_read+MFMA phase below)
    if (kt + 1 < KT_) {
      seg_offsets(kt + 1, UBASE, aoffk, woffk);
      STAGE_TILES(cur ^ 1, aoffk, woffk);
    }
    // phase 2: compute current tile from LDS
    const int abase = cur * 1280;
    const int bbase = cur * 1024;
    #pragma unroll
    for (int ks = 0; ks < 2; ++ks) {
      bf16x8 af[5], bb[4];
      #pragma unroll
      for (int mi = 0; mi < 5; ++mi) af[mi] = ldsA[abase + ks * 640 + aoff + mi * 64];
      #pragma unroll
      for (int ni = 0; ni < 4; ++ni) bb[ni] = ldsB[bbase + ks * 512 + boff + ni * 64];
      #pragma unroll
      for (int mi = 0; mi < 5; ++mi)
        #pragma unroll
        for (int ni = 0; ni < 4; ++ni)
          acc[mi][ni] = __builtin_amdgcn_mfma_f32_16x16x32_bf16(af[mi], bb[ni], acc[mi][ni], 0, 0, 0);
    }
    // single drain+barrier per iteration: next tile's loads had the whole MFMA phase
    // to complete; all waves finished reading `cur` before anyone re-stages it.
    asm volatile("s_waitcnt vmcnt(0)" ::: "memory");
    __syncthreads();
    cur ^= 1;
  }

  // epilogue: C/D layout col = lane&15, row = (lane>>4)*4 + reg
  #pragma unroll
  for (int mi = 0; mi < 5; ++mi) {
    #pragma unroll
    for (int p = 0; p < 4; ++p) {
      const int m = m0 + wm + mi * 16 + l4 * 4 + p;
      #pragma unroll
      for (int ni = 0; ni < 4; ++ni) {
        const int n = n0 + wn + ni * 16 + l15;
        float v = acc[mi][ni][p];
        if (IS_ZR) {
          if (n < 1024) {
            zbuf[(size_t)m * 1024 + n] = sigm_(v + bw1[n] + bu1[n]);
          } else {
            const int nn2 = n - 1024;
            float r = sigm_(v + bw2[nn2] + bu2[nn2]);
            float rh = r * hcur[(size_t)m * 1024 + nn2];
            __hip_bfloat16 hi, lo; split_bf16(rh, hi, lo);
            rhbase[(size_t)m * SA_ + 6144 + nn2] = hi;
            rhbase[(size_t)m * SA_ + 7168 + nn2] = lo;
          }
        } else {
          float hc = tanh_(v + bw1[n] + bu1[n]);
          float z  = zbuf[(size_t)m * 1024 + n];
          float ho = hcur[(size_t)m * 1024 + n];
          hout[(size_t)m * 1024 + n] = (1.0f - z) * ho + z * hc;
        }
      }
    }
  }
}

extern "C" void kernel_launch(void* const* d_in, const int* in_sizes, int n_in,
                              void* d_out, int out_size, void* d_ws, size_t ws_size,
                              hipStream_t stream) {
  const float* x    = (const float*)d_in[0];
  const float* inM  = (const float*)d_in[1];
  const float* outM = (const float*)d_in[2];
  const float* W1w  = (const float*)d_in[3];
  const float* b1w  = (const float*)d_in[4];
  const float* W1u  = (const float*)d_in[5];
  const float* b1u  = (const float*)d_in[6];
  const float* W2w  = (const float*)d_in[7];
  const float* b2w  = (const float*)d_in[8];
  const float* W2u  = (const float*)d_in[9];
  const float* b2u  = (const float*)d_in[10];
  const float* W3w  = (const float*)d_in[11];
  const float* b3w  = (const float*)d_in[12];
  const float* W3u  = (const float*)d_in[13];
  const float* b3u  = (const float*)d_in[14];
  float* hout = (float*)d_out;   // h lives in d_out across timesteps

  char* ws = (char*)d_ws;
  __hip_bfloat16* Wzr = (__hip_bfloat16*)ws;                 // 2048*6144*2 = 25,165,824 B
  __hip_bfloat16* Wh  = (__hip_bfloat16*)(ws + 25165824);    // 1024*6144*2 = 12,582,912 B
  const size_t fixed = 37748736;
  // per-batch-element chunk cost: Abuf 80*SA_*2 + zbuf 80*1024*4 = 1,638,400 B
  int Rb = 256;                                              // batch elems per chunk (mult of 8)
  while (Rb > 8 && fixed + (size_t)Rb * 1638400ull > ws_size) Rb -= 8;
  float* zbuf = (float*)(ws + fixed);                        // Rb*80*1024*4
  __hip_bfloat16* Abuf = (__hip_bfloat16*)(ws + fixed + (size_t)Rb * 327680ull);

  pack_weights<<<(3072 * 3072) / 256, 256, 0, stream>>>(
      W1w, W1u, W2w, W2u, W3w, W3u, Wzr, Wh);

  for (int t = 0; t < 3; ++t) {
    const float* hsrc = (t == 0) ? x : (const float*)hout;
    for (int b0 = 0; b0 < B_; b0 += Rb) {
      const int nb = (B_ - b0 < Rb) ? (B_ - b0) : Rb;
      const int rows = N_ * nb;                  // 80*nb, nb mult of 8 -> /160 integral
      const int mtiles = rows / 160;
      const float* hc = hsrc + (size_t)b0 * N_ * D_;
      prop_kernel<<<dim3(nb, D_ / 256), 256, 0, stream>>>(hc, inM, outM, Abuf);
      gemm_kernel<true><<<mtiles * 16, 256, 0, stream>>>(
          Abuf, Wzr, b1w, b1u, b2w, b2u, hc, zbuf, Abuf, nullptr, mtiles);
      gemm_kernel<false><<<mtiles * 8, 256, 0, stream>>>(
          Abuf, Wh, b3w, b3u, nullptr, nullptr, hc, zbuf, nullptr,
          hout + (size_t)b0 * N_ * D_, mtiles);
    }
  }
}

// Round 2
// 6300.881 us; speedup vs baseline: 1.0752x; 1.0752x over previous
//
#include <hip/hip_runtime.h>
#include <hip/hip_bf16.h>
#include <stdint.h>

// GatedGNN: B=256, N=80, D=1024, T=3
#define B_   256
#define N_   80
#define D_   1024
#define M_   (B_*N_)     // 20480 rows (b*80+node)
// Abuf row (bf16), SA_=8192: [a_hi(0:2048)|a_lo(2048:4096)|h_hi(4096:5120)|h_lo(5120:6144)|rh_hi(6144:7168)|rh_lo(7168:8192)]
#define SA_  8192
// W row (bf16), SW_=6144: [w_a_hi(0:2048)|w_a_lo(2048:4096)|w_u_hi(4096:5120)|w_u_lo(5120:6144)]
#define SW_  6144
#define KT_  144         // 144 BK=64 tiles -> K_eff = 9216 (3-term split product)

typedef __attribute__((ext_vector_type(8))) short bf16x8;   // 8 bf16 = 4 VGPRs
typedef __attribute__((ext_vector_type(4))) float f32x4;

__device__ __forceinline__ void async_cp16(const void* g, void* l) {
  __builtin_amdgcn_global_load_lds((const __attribute__((address_space(1))) unsigned int*)g,
                                   (__attribute__((address_space(3))) unsigned int*)l,
                                   16, 0, 0);
}
__device__ __forceinline__ float sigm_(float x) { return 1.0f / (1.0f + __expf(-x)); }
__device__ __forceinline__ float tanh_(float x) { return 2.0f / (1.0f + __expf(-2.0f * x)) - 1.0f; }
__device__ __forceinline__ void split_bf16(float v, __hip_bfloat16& hi, __hip_bfloat16& lo) {
  hi = __float2bfloat16(v);
  lo = __float2bfloat16(v - __bfloat162float(hi));
}

// ---------------- weight packing (hi/lo split): Wzr[2048][SW_], Wh[1024][SW_] ------------------
__global__ __launch_bounds__(256) void pack_weights(
    const float* __restrict__ W1w, const float* __restrict__ W1u,
    const float* __restrict__ W2w, const float* __restrict__ W2u,
    const float* __restrict__ W3w, const float* __restrict__ W3u,
    __hip_bfloat16* __restrict__ Wzr, __hip_bfloat16* __restrict__ Wh) {
  int idx = blockIdx.x * 256 + threadIdx.x;     // [0, 3072*3072)
  int n = idx / 3072, k = idx - n * 3072;       // n: 0..3071 output row, k: source col
  const float *Ww, *Wu; int nr; __hip_bfloat16* outrow;
  if (n < 1024)      { Ww = W1w; Wu = W1u; nr = n;        outrow = Wzr + (size_t)n * SW_; }
  else if (n < 2048) { Ww = W2w; Wu = W2u; nr = n - 1024; outrow = Wzr + (size_t)n * SW_; }
  else               { Ww = W3w; Wu = W3u; nr = n - 2048; outrow = Wh + (size_t)(n - 2048) * SW_; }
  float v; int chi, clo;
  if (k < 2048) { v = Ww[nr * 2048 + k];          chi = k;               clo = 2048 + k; }
  else          { v = Wu[nr * 1024 + (k - 2048)]; chi = 4096 + (k-2048); clo = 5120 + (k - 2048); }
  __hip_bfloat16 hi, lo; split_bf16(v, hi, lo);
  outrow[chi] = hi; outrow[clo] = lo;
}

// ---------------- propagation: a_in/a_out = inM/outM @ h[b] (fp32), split -> Abuf --------------
__global__ __launch_bounds__(256) void prop_kernel(
    const float* __restrict__ h, const float* __restrict__ inM,
    const float* __restrict__ outM, __hip_bfloat16* __restrict__ Abuf) {
  const int b = blockIdx.x;                        // chunk-local batch index
  const int d = blockIdx.y * 256 + threadIdx.x;
  const float* hb = h + (size_t)b * N_ * D_ + d;
  float hreg[N_];
  #pragma unroll
  for (int m = 0; m < N_; ++m) hreg[m] = hb[m * D_];
  __hip_bfloat16* Ab = Abuf + (size_t)b * N_ * SA_;
  #pragma unroll
  for (int m = 0; m < N_; ++m) {
    __hip_bfloat16 hi, lo; split_bf16(hreg[m], hi, lo);
    Ab[m * SA_ + 4096 + d] = hi; Ab[m * SA_ + 5120 + d] = lo;
  }
  for (int n = 0; n < N_; ++n) {
    float ai = 0.f, ao = 0.f;
    #pragma unroll
    for (int m = 0; m < N_; ++m) {
      ai += inM[n * N_ + m] * hreg[m];
      ao += outM[n * N_ + m] * hreg[m];
    }
    __hip_bfloat16 hi, lo;
    split_bf16(ai, hi, lo); Ab[n * SA_ + d] = hi;        Ab[n * SA_ + 2048 + d] = lo;
    split_bf16(ao, hi, lo); Ab[n * SA_ + 1024 + d] = hi; Ab[n * SA_ + 3072 + d] = lo;
  }
}

// ---------------- MFMA GEMM, 160x128 tile, BK=64, 3-term split-bf16 K plan --------------------
// wave-grid 2x2, wave-tile 80m x 64n, acc 5x4 (80 AGPR). 36 KB LDS.
// R1 lesson: cross-block wave overlap IS the pipeline on this structure (explicit dbuf at
// 2 blocks/CU regressed 660->805 us; __syncthreads drains vmcnt(0) regardless). So maximize
// residency: 36 KB x 4 = 144 KB < 160 KB -> __launch_bounds__(256,4) = 4 blocks/CU.
// Rounds become exact: ZR 2048/1024 = 2.0, H 1024/1024 = 1.0 (removes H's 1.33-round tail).
template<bool IS_ZR>
__global__ __launch_bounds__(256, 4) void gemm_kernel(
    const __hip_bfloat16* __restrict__ Abuf,   // [rows][SA_] chunk-local
    const __hip_bfloat16* __restrict__ W,      // [Nout][SW_]
    const float* __restrict__ bw1, const float* __restrict__ bu1,
    const float* __restrict__ bw2, const float* __restrict__ bu2,
    const float* __restrict__ hcur,            // [rows][1024] fp32, chunk-local
    float* __restrict__ zbuf,                  // [rows][1024] fp32, chunk-local
    __hip_bfloat16* __restrict__ rhbase,       // = Abuf (rh at cols 6144/7168)
    float* __restrict__ hout,
    int mtiles) {
  __shared__ bf16x8 ldsA[1280];   // 20 KB: ks(2) x 160 m-rows x 4 chunks
  __shared__ bf16x8 ldsB[1024];   // 16 KB: ks(2) x 128 n-rows x 4 chunks

  const int ntiles = IS_ZR ? 16 : 8;           // 128-wide n tiles
  int mt, nt;
  if ((mtiles & 7) == 0) {
    const int flat = blockIdx.x;
    const int strip = mtiles >> 3;             // m-tiles per XCD
    const int xcd = flat & 7;
    const int loc = flat >> 3;                 // [0, strip*ntiles)
    mt = xcd * strip + loc / ntiles;
    nt = loc - (loc / ntiles) * ntiles;
  } else {
    mt = blockIdx.x / ntiles;
    nt = blockIdx.x - mt * ntiles;
  }
  const int m0 = mt * 160;
  const int n0 = nt * 128;

  const int tid  = threadIdx.x;
  const int lane = tid & 63;
  const int wave = tid >> 6;
  const int wm   = (wave & 1) * 80;
  const int wn   = (wave >> 1) * 64;
  const int l15  = lane & 15;
  const int l4   = lane >> 4;
  const int UBASE = IS_ZR ? 4096 : 6144;   // u-operand: h for ZR, r*h for H

  f32x4 acc[5][4];
  #pragma unroll
  for (int i = 0; i < 5; ++i)
    #pragma unroll
    for (int j = 0; j < 4; ++j) acc[i][j] = (f32x4){0.f, 0.f, 0.f, 0.f};

  const int aoff = (wm + l15) * 4 + l4;
  const int boff = (wn + l15) * 4 + l4;

  for (int kt = 0; kt < KT_; ++kt) {
    // segment plan: [0,32) a_hi*w_hi  [32,64) a_lo*w_hi  [64,96) a_hi*w_lo
    //               [96,112) u_hi*wu_hi [112,128) u_lo*wu_hi [128,144) u_hi*wu_lo
    int aoffk, woffk;
    if (kt < 64)       { aoffk = kt * 64;          woffk = (kt < 32) ? kt * 64 : kt * 64 - 2048; }
    else if (kt < 96)  { aoffk = kt * 64 - 4096;   woffk = kt * 64 - 2048; }
    else if (kt < 112) { int r = (kt - 96) * 64;  aoffk = UBASE + r;        woffk = 4096 + r; }
    else if (kt < 128) { int r = (kt - 112) * 64; aoffk = UBASE + 1024 + r; woffk = 4096 + r; }
    else               { int r = (kt - 128) * 64; aoffk = UBASE + r;        woffk = 5120 + r; }
    #pragma unroll
    for (int i = 0; i < 5; ++i) {              // A: 1280 chunks, 5 per thread
      const int cidx = i * 256 + tid;
      const int ks = cidx / 640;
      const int rr = cidx - ks * 640;
      const int q  = rr & 3;
      const int mm = rr >> 2;
      async_cp16(Abuf + (size_t)(m0 + mm) * SA_ + aoffk + ks * 32 + q * 8, &ldsA[cidx]);
    }
    #pragma unroll
    for (int j = 0; j < 4; ++j) {              // B: 1024 chunks, 4 per thread
      const int cidx = j * 256 + tid;
      const int q  = cidx & 3;
      const int nn = (cidx >> 2) & 127;
      const int ks = cidx >> 9;
      async_cp16(W + (size_t)(n0 + nn) * SW_ + woffk + ks * 32 + q * 8, &ldsB[cidx]);
    }
    asm volatile("s_waitcnt vmcnt(0)" ::: "memory");
    __syncthreads();
    #pragma unroll
    for (int ks = 0; ks < 2; ++ks) {
      bf16x8 af[5], bb[4];
      #pragma unroll
      for (int mi = 0; mi < 5; ++mi) af[mi] = ldsA[ks * 640 + aoff + mi * 64];
      #pragma unroll
      for (int ni = 0; ni < 4; ++ni) bb[ni] = ldsB[ks * 512 + boff + ni * 64];
      #pragma unroll
      for (int mi = 0; mi < 5; ++mi)
        #pragma unroll
        for (int ni = 0; ni < 4; ++ni)
          acc[mi][ni] = __builtin_amdgcn_mfma_f32_16x16x32_bf16(af[mi], bb[ni], acc[mi][ni], 0, 0, 0);
    }
    __syncthreads();
  }

  // epilogue: C/D layout col = lane&15, row = (lane>>4)*4 + reg
  #pragma unroll
  for (int mi = 0; mi < 5; ++mi) {
    #pragma unroll
    for (int p = 0; p < 4; ++p) {
      const int m = m0 + wm + mi * 16 + l4 * 4 + p;
      #pragma unroll
      for (int ni = 0; ni < 4; ++ni) {
        const int n = n0 + wn + ni * 16 + l15;
        float v = acc[mi][ni][p];
        if (IS_ZR) {
          if (n < 1024) {
            zbuf[(size_t)m * 1024 + n] = sigm_(v + bw1[n] + bu1[n]);
          } else {
            const int nn2 = n - 1024;
            float r = sigm_(v + bw2[nn2] + bu2[nn2]);
            float rh = r * hcur[(size_t)m * 1024 + nn2];
            __hip_bfloat16 hi, lo; split_bf16(rh, hi, lo);
            rhbase[(size_t)m * SA_ + 6144 + nn2] = hi;
            rhbase[(size_t)m * SA_ + 7168 + nn2] = lo;
          }
        } else {
          float hc = tanh_(v + bw1[n] + bu1[n]);
          float z  = zbuf[(size_t)m * 1024 + n];
          float ho = hcur[(size_t)m * 1024 + n];
          hout[(size_t)m * 1024 + n] = (1.0f - z) * ho + z * hc;
        }
      }
    }
  }
}

extern "C" void kernel_launch(void* const* d_in, const int* in_sizes, int n_in,
                              void* d_out, int out_size, void* d_ws, size_t ws_size,
                              hipStream_t stream) {
  const float* x    = (const float*)d_in[0];
  const float* inM  = (const float*)d_in[1];
  const float* outM = (const float*)d_in[2];
  const float* W1w  = (const float*)d_in[3];
  const float* b1w  = (const float*)d_in[4];
  const float* W1u  = (const float*)d_in[5];
  const float* b1u  = (const float*)d_in[6];
  const float* W2w  = (const float*)d_in[7];
  const float* b2w  = (const float*)d_in[8];
  const float* W2u  = (const float*)d_in[9];
  const float* b2u  = (const float*)d_in[10];
  const float* W3w  = (const float*)d_in[11];
  const float* b3w  = (const float*)d_in[12];
  const float* W3u  = (const float*)d_in[13];
  const float* b3u  = (const float*)d_in[14];
  float* hout = (float*)d_out;   // h lives in d_out across timesteps

  char* ws = (char*)d_ws;
  __hip_bfloat16* Wzr = (__hip_bfloat16*)ws;                 // 2048*6144*2 = 25,165,824 B
  __hip_bfloat16* Wh  = (__hip_bfloat16*)(ws + 25165824);    // 1024*6144*2 = 12,582,912 B
  const size_t fixed = 37748736;
  // per-batch-element chunk cost: Abuf 80*SA_*2 + zbuf 80*1024*4 = 1,638,400 B
  int Rb = 256;                                              // batch elems per chunk (mult of 8)
  while (Rb > 8 && fixed + (size_t)Rb * 1638400ull > ws_size) Rb -= 8;
  float* zbuf = (float*)(ws + fixed);                        // Rb*80*1024*4
  __hip_bfloat16* Abuf = (__hip_bfloat16*)(ws + fixed + (size_t)Rb * 327680ull);

  pack_weights<<<(3072 * 3072) / 256, 256, 0, stream>>>(
      W1w, W1u, W2w, W2u, W3w, W3u, Wzr, Wh);

  for (int t = 0; t < 3; ++t) {
    const float* hsrc = (t == 0) ? x : (const float*)hout;
    for (int b0 = 0; b0 < B_; b0 += Rb) {
      const int nb = (B_ - b0 < Rb) ? (B_ - b0) : Rb;
      const int rows = N_ * nb;                  // 80*nb, nb mult of 8 -> /160 integral
      const int mtiles = rows / 160;
      const float* hc = hsrc + (size_t)b0 * N_ * D_;
      prop_kernel<<<dim3(nb, D_ / 256), 256, 0, stream>>>(hc, inM, outM, Abuf);
      gemm_kernel<true><<<mtiles * 16, 256, 0, stream>>>(
          Abuf, Wzr, b1w, b1u, b2w, b2u, hc, zbuf, Abuf, nullptr, mtiles);
      gemm_kernel<false><<<mtiles * 8, 256, 0, stream>>>(
          Abuf, Wh, b3w, b3u, nullptr, nullptr, hc, zbuf, nullptr,
          hout + (size_t)b0 * N_ * D_, mtiles);
    }
  }
}

// Round 3
// 4924.078 us; speedup vs baseline: 1.3758x; 1.2796x over previous
//
#include <hip/hip_runtime.h>
#include <hip/hip_bf16.h>
#include <stdint.h>

// GatedGNN: B=256, N=80, D=1024, T=3
#define B_   256
#define N_   80
#define D_   1024
#define M_   (B_*N_)     // 20480 rows (b*80+node)
// Abuf row (bf16), SA_=8192: [a_hi(0:2048)|a_lo(2048:4096)|h_hi(4096:5120)|h_lo(5120:6144)|rh_hi(6144:7168)|rh_lo(7168:8192)]
#define SA_  8192
// W row (bf16), SW_=6144: [w_a_hi(0:2048)|w_a_lo(2048:4096)|w_u_hi(4096:5120)|w_u_lo(5120:6144)]
#define SW_  6144
// R3: combined-plane staging at BK=32. 96 chunks: [0,64) a-part (K=2048), [64,96) u-part (K=1024).
// Per chunk stage a_hi,a_lo,w_hi,w_lo once (36 KB, same LDS as before) and run all 3 split
// products from LDS: 240 MFMA/barrier (was 160), total staged bytes -33% (144x36KB -> 96x36KB).
#define KT_  96

typedef __attribute__((ext_vector_type(8))) short bf16x8;   // 8 bf16 = 4 VGPRs
typedef __attribute__((ext_vector_type(4))) float f32x4;

__device__ __forceinline__ void async_cp16(const void* g, void* l) {
  __builtin_amdgcn_global_load_lds((const __attribute__((address_space(1))) unsigned int*)g,
                                   (__attribute__((address_space(3))) unsigned int*)l,
                                   16, 0, 0);
}
__device__ __forceinline__ float sigm_(float x) { return 1.0f / (1.0f + __expf(-x)); }
__device__ __forceinline__ float tanh_(float x) { return 2.0f / (1.0f + __expf(-2.0f * x)) - 1.0f; }
__device__ __forceinline__ void split_bf16(float v, __hip_bfloat16& hi, __hip_bfloat16& lo) {
  hi = __float2bfloat16(v);
  lo = __float2bfloat16(v - __bfloat162float(hi));
}

// ---------------- weight packing (hi/lo split): Wzr[2048][SW_], Wh[1024][SW_] ------------------
__global__ __launch_bounds__(256) void pack_weights(
    const float* __restrict__ W1w, const float* __restrict__ W1u,
    const float* __restrict__ W2w, const float* __restrict__ W2u,
    const float* __restrict__ W3w, const float* __restrict__ W3u,
    __hip_bfloat16* __restrict__ Wzr, __hip_bfloat16* __restrict__ Wh) {
  int idx = blockIdx.x * 256 + threadIdx.x;     // [0, 3072*3072)
  int n = idx / 3072, k = idx - n * 3072;       // n: 0..3071 output row, k: source col
  const float *Ww, *Wu; int nr; __hip_bfloat16* outrow;
  if (n < 1024)      { Ww = W1w; Wu = W1u; nr = n;        outrow = Wzr + (size_t)n * SW_; }
  else if (n < 2048) { Ww = W2w; Wu = W2u; nr = n - 1024; outrow = Wzr + (size_t)n * SW_; }
  else               { Ww = W3w; Wu = W3u; nr = n - 2048; outrow = Wh + (size_t)(n - 2048) * SW_; }
  float v; int chi, clo;
  if (k < 2048) { v = Ww[nr * 2048 + k];          chi = k;               clo = 2048 + k; }
  else          { v = Wu[nr * 1024 + (k - 2048)]; chi = 4096 + (k-2048); clo = 5120 + (k - 2048); }
  __hip_bfloat16 hi, lo; split_bf16(v, hi, lo);
  outrow[chi] = hi; outrow[clo] = lo;
}

// ---------------- propagation: a_in/a_out = inM/outM @ h[b] (fp32), split -> Abuf --------------
__global__ __launch_bounds__(256) void prop_kernel(
    const float* __restrict__ h, const float* __restrict__ inM,
    const float* __restrict__ outM, __hip_bfloat16* __restrict__ Abuf) {
  const int b = blockIdx.x;                        // chunk-local batch index
  const int d = blockIdx.y * 256 + threadIdx.x;
  const float* hb = h + (size_t)b * N_ * D_ + d;
  float hreg[N_];
  #pragma unroll
  for (int m = 0; m < N_; ++m) hreg[m] = hb[m * D_];
  __hip_bfloat16* Ab = Abuf + (size_t)b * N_ * SA_;
  #pragma unroll
  for (int m = 0; m < N_; ++m) {
    __hip_bfloat16 hi, lo; split_bf16(hreg[m], hi, lo);
    Ab[m * SA_ + 4096 + d] = hi; Ab[m * SA_ + 5120 + d] = lo;
  }
  for (int n = 0; n < N_; ++n) {
    float ai = 0.f, ao = 0.f;
    #pragma unroll
    for (int m = 0; m < N_; ++m) {
      ai += inM[n * N_ + m] * hreg[m];
      ao += outM[n * N_ + m] * hreg[m];
    }
    __hip_bfloat16 hi, lo;
    split_bf16(ai, hi, lo); Ab[n * SA_ + d] = hi;        Ab[n * SA_ + 2048 + d] = lo;
    split_bf16(ao, hi, lo); Ab[n * SA_ + 1024 + d] = hi; Ab[n * SA_ + 3072 + d] = lo;
  }
}

// ---------------- MFMA GEMM, 160x128 tile, BK=32 x 4 planes, 3-term split-bf16 ----------------
// wave-grid 2x2, wave-tile 80m x 64n, acc 5x4 (80 AGPR). 36 KB LDS, 3 blocks/CU (R0-proven:
// 2 blocks/CU = 805us, 4 blocks/CU reg-squeezed = 800us, 3 = 660us).
// LDS layout: ldsA[plane(2)][row(160)][chunk(4)]  ldsB[plane(2)][row(128)][chunk(4)]
//   plane 0 = hi, plane 1 = lo; chunk = 16B = 8 bf16 of the 32-wide K slice.
// Per iter: stage 36 KB once, compute a_hi*w_hi + a_lo*w_hi + a_hi*w_lo (240 MFMA) from LDS.
template<bool IS_ZR>
__global__ __launch_bounds__(256, 3) void gemm_kernel(
    const __hip_bfloat16* __restrict__ Abuf,   // [rows][SA_] chunk-local
    const __hip_bfloat16* __restrict__ W,      // [Nout][SW_]
    const float* __restrict__ bw1, const float* __restrict__ bu1,
    const float* __restrict__ bw2, const float* __restrict__ bu2,
    const float* __restrict__ hcur,            // [rows][1024] fp32, chunk-local
    float* __restrict__ zbuf,                  // [rows][1024] fp32, chunk-local
    __hip_bfloat16* __restrict__ rhbase,       // = Abuf (rh at cols 6144/7168)
    float* __restrict__ hout,
    int mtiles) {
  __shared__ bf16x8 ldsA[1280];   // 20 KB: plane(2) x 160 m-rows x 4 chunks
  __shared__ bf16x8 ldsB[1024];   // 16 KB: plane(2) x 128 n-rows x 4 chunks

  const int ntiles = IS_ZR ? 16 : 8;           // 128-wide n tiles
  int mt, nt;
  if ((mtiles & 7) == 0) {
    const int flat = blockIdx.x;
    const int strip = mtiles >> 3;             // m-tiles per XCD
    const int xcd = flat & 7;
    const int loc = flat >> 3;                 // [0, strip*ntiles)
    mt = xcd * strip + loc / ntiles;
    nt = loc - (loc / ntiles) * ntiles;
  } else {
    mt = blockIdx.x / ntiles;
    nt = blockIdx.x - mt * ntiles;
  }
  const int m0 = mt * 160;
  const int n0 = nt * 128;

  const int tid  = threadIdx.x;
  const int lane = tid & 63;
  const int wave = tid >> 6;
  const int wm   = (wave & 1) * 80;
  const int wn   = (wave >> 1) * 64;
  const int l15  = lane & 15;
  const int l4   = lane >> 4;
  const int UBASE = IS_ZR ? 4096 : 6144;   // u-operand: h for ZR, r*h for H

  f32x4 acc[5][4];
  #pragma unroll
  for (int i = 0; i < 5; ++i)
    #pragma unroll
    for (int j = 0; j < 4; ++j) acc[i][j] = (f32x4){0.f, 0.f, 0.f, 0.f};

  const int aoff = (wm + l15) * 4 + l4;
  const int boff = (wn + l15) * 4 + l4;

  for (int kt = 0; kt < KT_; ++kt) {
    // plane column offsets for this 32-wide K chunk
    int ahi, alo, whi, wlo;
    if (kt < 64) { const int c = kt * 32;        ahi = c;             alo = 2048 + c;
                   whi = c;                      wlo = 2048 + c; }
    else         { const int r = (kt - 64) * 32; ahi = UBASE + r;     alo = UBASE + 1024 + r;
                   whi = 4096 + r;               wlo = 5120 + r; }
    #pragma unroll
    for (int i = 0; i < 5; ++i) {              // A: 1280 chunks (2 planes x 160 x 4), 5/thread
      const int cidx = i * 256 + tid;
      const int pl = cidx / 640;               // 0 = hi, 1 = lo
      const int rr = cidx - pl * 640;
      const int q  = rr & 3;
      const int mm = rr >> 2;
      async_cp16(Abuf + (size_t)(m0 + mm) * SA_ + (pl ? alo : ahi) + q * 8, &ldsA[cidx]);
    }
    #pragma unroll
    for (int j = 0; j < 4; ++j) {              // B: 1024 chunks (2 planes x 128 x 4), 4/thread
      const int cidx = j * 256 + tid;
      const int pl = cidx >> 9;
      const int q  = cidx & 3;
      const int nn = (cidx >> 2) & 127;
      async_cp16(W + (size_t)(n0 + nn) * SW_ + (pl ? wlo : whi) + q * 8, &ldsB[cidx]);
    }
    asm volatile("s_waitcnt vmcnt(0)" ::: "memory");
    __syncthreads();

    // 3 split products from one staging; reads sequenced to cap live operands (~56 VGPR peak)
    bf16x8 af_h[5], af_l[5], bb_h[4], bb_l[4];
    #pragma unroll
    for (int mi = 0; mi < 5; ++mi) af_h[mi] = ldsA[aoff + mi * 64];
    #pragma unroll
    for (int ni = 0; ni < 4; ++ni) bb_h[ni] = ldsB[boff + ni * 64];
    #pragma unroll
    for (int mi = 0; mi < 5; ++mi)             // seg0: a_hi * w_hi
      #pragma unroll
      for (int ni = 0; ni < 4; ++ni)
        acc[mi][ni] = __builtin_amdgcn_mfma_f32_16x16x32_bf16(af_h[mi], bb_h[ni], acc[mi][ni], 0, 0, 0);
    #pragma unroll
    for (int mi = 0; mi < 5; ++mi) af_l[mi] = ldsA[640 + aoff + mi * 64];
    #pragma unroll
    for (int mi = 0; mi < 5; ++mi)             // seg1: a_lo * w_hi
      #pragma unroll
      for (int ni = 0; ni < 4; ++ni)
        acc[mi][ni] = __builtin_amdgcn_mfma_f32_16x16x32_bf16(af_l[mi], bb_h[ni], acc[mi][ni], 0, 0, 0);
    #pragma unroll
    for (int ni = 0; ni < 4; ++ni) bb_l[ni] = ldsB[512 + boff + ni * 64];
    #pragma unroll
    for (int mi = 0; mi < 5; ++mi)             // seg2: a_hi * w_lo
      #pragma unroll
      for (int ni = 0; ni < 4; ++ni)
        acc[mi][ni] = __builtin_amdgcn_mfma_f32_16x16x32_bf16(af_h[mi], bb_l[ni], acc[mi][ni], 0, 0, 0);

    __syncthreads();
  }

  // epilogue: C/D layout col = lane&15, row = (lane>>4)*4 + reg
  #pragma unroll
  for (int mi = 0; mi < 5; ++mi) {
    #pragma unroll
    for (int p = 0; p < 4; ++p) {
      const int m = m0 + wm + mi * 16 + l4 * 4 + p;
      #pragma unroll
      for (int ni = 0; ni < 4; ++ni) {
        const int n = n0 + wn + ni * 16 + l15;
        float v = acc[mi][ni][p];
        if (IS_ZR) {
          if (n < 1024) {
            zbuf[(size_t)m * 1024 + n] = sigm_(v + bw1[n] + bu1[n]);
          } else {
            const int nn2 = n - 1024;
            float r = sigm_(v + bw2[nn2] + bu2[nn2]);
            float rh = r * hcur[(size_t)m * 1024 + nn2];
            __hip_bfloat16 hi, lo; split_bf16(rh, hi, lo);
            rhbase[(size_t)m * SA_ + 6144 + nn2] = hi;
            rhbase[(size_t)m * SA_ + 7168 + nn2] = lo;
          }
        } else {
          float hc = tanh_(v + bw1[n] + bu1[n]);
          float z  = zbuf[(size_t)m * 1024 + n];
          float ho = hcur[(size_t)m * 1024 + n];
          hout[(size_t)m * 1024 + n] = (1.0f - z) * ho + z * hc;
        }
      }
    }
  }
}

extern "C" void kernel_launch(void* const* d_in, const int* in_sizes, int n_in,
                              void* d_out, int out_size, void* d_ws, size_t ws_size,
                              hipStream_t stream) {
  const float* x    = (const float*)d_in[0];
  const float* inM  = (const float*)d_in[1];
  const float* outM = (const float*)d_in[2];
  const float* W1w  = (const float*)d_in[3];
  const float* b1w  = (const float*)d_in[4];
  const float* W1u  = (const float*)d_in[5];
  const float* b1u  = (const float*)d_in[6];
  const float* W2w  = (const float*)d_in[7];
  const float* b2w  = (const float*)d_in[8];
  const float* W2u  = (const float*)d_in[9];
  const float* b2u  = (const float*)d_in[10];
  const float* W3w  = (const float*)d_in[11];
  const float* b3w  = (const float*)d_in[12];
  const float* W3u  = (const float*)d_in[13];
  const float* b3u  = (const float*)d_in[14];
  float* hout = (float*)d_out;   // h lives in d_out across timesteps

  char* ws = (char*)d_ws;
  __hip_bfloat16* Wzr = (__hip_bfloat16*)ws;                 // 2048*6144*2 = 25,165,824 B
  __hip_bfloat16* Wh  = (__hip_bfloat16*)(ws + 25165824);    // 1024*6144*2 = 12,582,912 B
  const size_t fixed = 37748736;
  // per-batch-element chunk cost: Abuf 80*SA_*2 + zbuf 80*1024*4 = 1,638,400 B
  int Rb = 256;                                              // batch elems per chunk (mult of 8)
  while (Rb > 8 && fixed + (size_t)Rb * 1638400ull > ws_size) Rb -= 8;
  float* zbuf = (float*)(ws + fixed);                        // Rb*80*1024*4
  __hip_bfloat16* Abuf = (__hip_bfloat16*)(ws + fixed + (size_t)Rb * 327680ull);

  pack_weights<<<(3072 * 3072) / 256, 256, 0, stream>>>(
      W1w, W1u, W2w, W2u, W3w, W3u, Wzr, Wh);

  for (int t = 0; t < 3; ++t) {
    const float* hsrc = (t == 0) ? x : (const float*)hout;
    for (int b0 = 0; b0 < B_; b0 += Rb) {
      const int nb = (B_ - b0 < Rb) ? (B_ - b0) : Rb;
      const int rows = N_ * nb;                  // 80*nb, nb mult of 8 -> /160 integral
      const int mtiles = rows / 160;
      const float* hc = hsrc + (size_t)b0 * N_ * D_;
      prop_kernel<<<dim3(nb, D_ / 256), 256, 0, stream>>>(hc, inM, outM, Abuf);
      gemm_kernel<true><<<mtiles * 16, 256, 0, stream>>>(
          Abuf, Wzr, b1w, b1u, b2w, b2u, hc, zbuf, Abuf, nullptr, mtiles);
      gemm_kernel<false><<<mtiles * 8, 256, 0, stream>>>(
          Abuf, Wh, b3w, b3u, nullptr, nullptr, hc, zbuf, nullptr,
          hout + (size_t)b0 * N_ * D_, mtiles);
    }
  }
}

// Round 4
// 4844.267 us; speedup vs baseline: 1.3984x; 1.0165x over previous
//
#include <hip/hip_runtime.h>
#include <hip/hip_bf16.h>
#include <stdint.h>

// GatedGNN: B=256, N=80, D=1024, T=3
#define B_   256
#define N_   80
#define D_   1024
#define M_   (B_*N_)     // 20480 rows (b*80+node)
// Abuf row (bf16), SA_=8192: [a_hi(0:2048)|a_lo(2048:4096)|h_hi(4096:5120)|h_lo(5120:6144)|rh_hi(6144:7168)|rh_lo(7168:8192)]
#define SA_  8192
// W row (bf16), SW_=6144: [w_a_hi(0:2048)|w_a_lo(2048:4096)|w_u_hi(4096:5120)|w_u_lo(5120:6144)]
#define SW_  6144
// Combined-plane staging at BK=32. 96 chunks: [0,64) a-part (K=2048), [64,96) u-part (K=1024).
#define KT_  96

typedef __attribute__((ext_vector_type(8))) short bf16x8;   // 8 bf16 = 4 VGPRs
typedef __attribute__((ext_vector_type(4))) float f32x4;

__device__ __forceinline__ void async_cp16(const void* g, void* l) {
  __builtin_amdgcn_global_load_lds((const __attribute__((address_space(1))) unsigned int*)g,
                                   (__attribute__((address_space(3))) unsigned int*)l,
                                   16, 0, 0);
}
__device__ __forceinline__ float sigm_(float x) { return 1.0f / (1.0f + __expf(-x)); }
__device__ __forceinline__ float tanh_(float x) { return 2.0f / (1.0f + __expf(-2.0f * x)) - 1.0f; }
__device__ __forceinline__ void split_bf16(float v, __hip_bfloat16& hi, __hip_bfloat16& lo) {
  hi = __float2bfloat16(v);
  lo = __float2bfloat16(v - __bfloat162float(hi));
}
__device__ __forceinline__ void plane_offsets(int kt, int UBASE, int& ahi, int& alo, int& whi, int& wlo) {
  if (kt < 64) { const int c = kt * 32;        ahi = c;         alo = 2048 + c;
                 whi = c;                      wlo = 2048 + c; }
  else         { const int r = (kt - 64) * 32; ahi = UBASE + r; alo = UBASE + 1024 + r;
                 whi = 4096 + r;               wlo = 5120 + r; }
}

// ---------------- weight packing (hi/lo split): Wzr[2048][SW_], Wh[1024][SW_] ------------------
__global__ __launch_bounds__(256) void pack_weights(
    const float* __restrict__ W1w, const float* __restrict__ W1u,
    const float* __restrict__ W2w, const float* __restrict__ W2u,
    const float* __restrict__ W3w, const float* __restrict__ W3u,
    __hip_bfloat16* __restrict__ Wzr, __hip_bfloat16* __restrict__ Wh) {
  int idx = blockIdx.x * 256 + threadIdx.x;     // [0, 3072*3072)
  int n = idx / 3072, k = idx - n * 3072;       // n: 0..3071 output row, k: source col
  const float *Ww, *Wu; int nr; __hip_bfloat16* outrow;
  if (n < 1024)      { Ww = W1w; Wu = W1u; nr = n;        outrow = Wzr + (size_t)n * SW_; }
  else if (n < 2048) { Ww = W2w; Wu = W2u; nr = n - 1024; outrow = Wzr + (size_t)n * SW_; }
  else               { Ww = W3w; Wu = W3u; nr = n - 2048; outrow = Wh + (size_t)(n - 2048) * SW_; }
  float v; int chi, clo;
  if (k < 2048) { v = Ww[nr * 2048 + k];          chi = k;               clo = 2048 + k; }
  else          { v = Wu[nr * 1024 + (k - 2048)]; chi = 4096 + (k-2048); clo = 5120 + (k - 2048); }
  __hip_bfloat16 hi, lo; split_bf16(v, hi, lo);
  outrow[chi] = hi; outrow[clo] = lo;
}

// ---------------- propagation: a_in/a_out = inM/outM @ h[b] (fp32), split -> Abuf --------------
__global__ __launch_bounds__(256) void prop_kernel(
    const float* __restrict__ h, const float* __restrict__ inM,
    const float* __restrict__ outM, __hip_bfloat16* __restrict__ Abuf) {
  const int b = blockIdx.x;                        // chunk-local batch index
  const int d = blockIdx.y * 256 + threadIdx.x;
  const float* hb = h + (size_t)b * N_ * D_ + d;
  float hreg[N_];
  #pragma unroll
  for (int m = 0; m < N_; ++m) hreg[m] = hb[m * D_];
  __hip_bfloat16* Ab = Abuf + (size_t)b * N_ * SA_;
  #pragma unroll
  for (int m = 0; m < N_; ++m) {
    __hip_bfloat16 hi, lo; split_bf16(hreg[m], hi, lo);
    Ab[m * SA_ + 4096 + d] = hi; Ab[m * SA_ + 5120 + d] = lo;
  }
  for (int n = 0; n < N_; ++n) {
    float ai = 0.f, ao = 0.f;
    #pragma unroll
    for (int m = 0; m < N_; ++m) {
      ai += inM[n * N_ + m] * hreg[m];
      ao += outM[n * N_ + m] * hreg[m];
    }
    __hip_bfloat16 hi, lo;
    split_bf16(ai, hi, lo); Ab[n * SA_ + d] = hi;        Ab[n * SA_ + 2048 + d] = lo;
    split_bf16(ao, hi, lo); Ab[n * SA_ + 1024 + d] = hi; Ab[n * SA_ + 3072 + d] = lo;
  }
}

// ---------------- MFMA GEMM, 160x128 tile, BK=32 x 4 planes, 3-term split-bf16 ----------------
// wave-grid 2x2, wave-tile 80m x 64n, acc 5x4 (80 AGPR). 36 KB LDS single-buffer, 3 blocks/CU.
// R4 structure (self-overlap without LDS cost):
//   vmcnt(0); barrier            -> tile kt fully in LDS
//   ds_read all 18 operands      -> registers (barrier's lgkmcnt(0) drain completes them)
//   barrier                      -> every wave done with LDS; buffer is dead
//   STAGE(kt+1) into SAME buffer -> 9 async loads fly under the 60 MFMAs below
//   seg0 + seg1 + seg2 MFMAs     -> ~3492 cyc/CU covers ~1930 cyc/CU of L2 feed + latency
// Bank-conflict swizzle (rule #21: linear LDS dest, pre-swizzled GLOBAL source + swizzled read):
//   slot q holds global chunk q ^ ((row>>1)&3)  ->  (4*row + q') mod 8 covers all 8 16B-slots
//   evenly => 2-way aliasing only (free). Swizzle term invariant under row+=16, so +mi*64
//   indexing is unchanged.
template<bool IS_ZR>
__global__ __launch_bounds__(256, 3) void gemm_kernel(
    const __hip_bfloat16* __restrict__ Abuf,   // [rows][SA_] chunk-local
    const __hip_bfloat16* __restrict__ W,      // [Nout][SW_]
    const float* __restrict__ bw1, const float* __restrict__ bu1,
    const float* __restrict__ bw2, const float* __restrict__ bu2,
    const float* __restrict__ hcur,            // [rows][1024] fp32, chunk-local
    float* __restrict__ zbuf,                  // [rows][1024] fp32, chunk-local
    __hip_bfloat16* __restrict__ rhbase,       // = Abuf (rh at cols 6144/7168)
    float* __restrict__ hout,
    int mtiles) {
  __shared__ bf16x8 ldsA[1280];   // 20 KB: plane(2) x 160 m-rows x 4 chunks
  __shared__ bf16x8 ldsB[1024];   // 16 KB: plane(2) x 128 n-rows x 4 chunks

  const int ntiles = IS_ZR ? 16 : 8;           // 128-wide n tiles
  int mt, nt;
  if ((mtiles & 7) == 0) {
    const int flat = blockIdx.x;
    const int strip = mtiles >> 3;             // m-tiles per XCD
    const int xcd = flat & 7;
    const int loc = flat >> 3;                 // [0, strip*ntiles)
    mt = xcd * strip + loc / ntiles;
    nt = loc - (loc / ntiles) * ntiles;
  } else {
    mt = blockIdx.x / ntiles;
    nt = blockIdx.x - mt * ntiles;
  }
  const int m0 = mt * 160;
  const int n0 = nt * 128;

  const int tid  = threadIdx.x;
  const int lane = tid & 63;
  const int wave = tid >> 6;
  const int wm   = (wave & 1) * 80;
  const int wn   = (wave >> 1) * 64;
  const int l15  = lane & 15;
  const int l4   = lane >> 4;
  const int UBASE = IS_ZR ? 4096 : 6144;   // u-operand: h for ZR, r*h for H

  f32x4 acc[5][4];
  #pragma unroll
  for (int i = 0; i < 5; ++i)
    #pragma unroll
    for (int j = 0; j < 4; ++j) acc[i][j] = (f32x4){0.f, 0.f, 0.f, 0.f};

  // swizzled, loop-invariant operand read offsets (slot units of 16B)
  const int arow = wm + l15;
  const int brow = wn + l15;
  const int aoff = arow * 4 + (l4 ^ ((arow >> 1) & 3));
  const int boff = brow * 4 + (l4 ^ ((brow >> 1) & 3));

  // staging: issues 9 async 16B copies for tile kt (columns ahi/alo/whi/wlo),
  // global chunk pre-swizzled by q ^ ((row>>1)&3); LDS destination linear.
  #define STAGE_TILE(AHI, ALO, WHI, WLO) do {                                                  \
      _Pragma("unroll")                                                                        \
      for (int i_ = 0; i_ < 5; ++i_) {            /* A: 1280 slots (2 pl x 160 x 4) */         \
        const int cidx = i_ * 256 + tid;                                                       \
        const int pl = cidx / 640;                                                             \
        const int rr = cidx - pl * 640;                                                        \
        const int q  = rr & 3;                                                                 \
        const int mm = rr >> 2;                                                                \
        const int qg = q ^ ((mm >> 1) & 3);                                                    \
        async_cp16(Abuf + (size_t)(m0 + mm) * SA_ + (pl ? (ALO) : (AHI)) + qg * 8,             \
                   &ldsA[cidx]);                                                               \
      }                                                                                        \
      _Pragma("unroll")                                                                        \
      for (int j_ = 0; j_ < 4; ++j_) {            /* B: 1024 slots (2 pl x 128 x 4) */         \
        const int cidx = j_ * 256 + tid;                                                       \
        const int pl = cidx >> 9;                                                              \
        const int q  = cidx & 3;                                                               \
        const int nn = (cidx >> 2) & 127;                                                      \
        const int qg = q ^ ((nn >> 1) & 3);                                                    \
        async_cp16(W + (size_t)(n0 + nn) * SW_ + (pl ? (WLO) : (WHI)) + qg * 8,                \
                   &ldsB[cidx]);                                                               \
      }                                                                                        \
    } while (0)

  // prologue: stage tile 0
  int ahi, alo, whi, wlo;
  plane_offsets(0, UBASE, ahi, alo, whi, wlo);
  STAGE_TILE(ahi, alo, whi, wlo);

  for (int kt = 0; kt < KT_; ++kt) {
    asm volatile("s_waitcnt vmcnt(0)" ::: "memory");   // this wave's stage writes landed
    __syncthreads();                                   // tile kt visible to all waves

    // read ALL operands to registers; the next barrier's lgkmcnt(0) drain completes them
    bf16x8 af_h[5], af_l[5], bb_h[4], bb_l[4];
    #pragma unroll
    for (int mi = 0; mi < 5; ++mi) { af_h[mi] = ldsA[aoff + mi * 64];
                                     af_l[mi] = ldsA[640 + aoff + mi * 64]; }
    #pragma unroll
    for (int ni = 0; ni < 4; ++ni) { bb_h[ni] = ldsB[boff + ni * 64];
                                     bb_l[ni] = ldsB[512 + boff + ni * 64]; }
    __syncthreads();                                   // all waves done with LDS -> reusable

    if (kt + 1 < KT_) {                                // stage kt+1 under the MFMAs below
      plane_offsets(kt + 1, UBASE, ahi, alo, whi, wlo);
      STAGE_TILE(ahi, alo, whi, wlo);
    }

    #pragma unroll
    for (int mi = 0; mi < 5; ++mi)             // seg0: a_hi * w_hi
      #pragma unroll
      for (int ni = 0; ni < 4; ++ni)
        acc[mi][ni] = __builtin_amdgcn_mfma_f32_16x16x32_bf16(af_h[mi], bb_h[ni], acc[mi][ni], 0, 0, 0);
    #pragma unroll
    for (int mi = 0; mi < 5; ++mi)             // seg1: a_lo * w_hi
      #pragma unroll
      for (int ni = 0; ni < 4; ++ni)
        acc[mi][ni] = __builtin_amdgcn_mfma_f32_16x16x32_bf16(af_l[mi], bb_h[ni], acc[mi][ni], 0, 0, 0);
    #pragma unroll
    for (int mi = 0; mi < 5; ++mi)             // seg2: a_hi * w_lo
      #pragma unroll
      for (int ni = 0; ni < 4; ++ni)
        acc[mi][ni] = __builtin_amdgcn_mfma_f32_16x16x32_bf16(af_h[mi], bb_l[ni], acc[mi][ni], 0, 0, 0);
  }
  #undef STAGE_TILE

  // epilogue: C/D layout col = lane&15, row = (lane>>4)*4 + reg
  #pragma unroll
  for (int mi = 0; mi < 5; ++mi) {
    #pragma unroll
    for (int p = 0; p < 4; ++p) {
      const int m = m0 + wm + mi * 16 + l4 * 4 + p;
      #pragma unroll
      for (int ni = 0; ni < 4; ++ni) {
        const int n = n0 + wn + ni * 16 + l15;
        float v = acc[mi][ni][p];
        if (IS_ZR) {
          if (n < 1024) {
            zbuf[(size_t)m * 1024 + n] = sigm_(v + bw1[n] + bu1[n]);
          } else {
            const int nn2 = n - 1024;
            float r = sigm_(v + bw2[nn2] + bu2[nn2]);
            float rh = r * hcur[(size_t)m * 1024 + nn2];
            __hip_bfloat16 hi, lo; split_bf16(rh, hi, lo);
            rhbase[(size_t)m * SA_ + 6144 + nn2] = hi;
            rhbase[(size_t)m * SA_ + 7168 + nn2] = lo;
          }
        } else {
          float hc = tanh_(v + bw1[n] + bu1[n]);
          float z  = zbuf[(size_t)m * 1024 + n];
          float ho = hcur[(size_t)m * 1024 + n];
          hout[(size_t)m * 1024 + n] = (1.0f - z) * ho + z * hc;
        }
      }
    }
  }
}

extern "C" void kernel_launch(void* const* d_in, const int* in_sizes, int n_in,
                              void* d_out, int out_size, void* d_ws, size_t ws_size,
                              hipStream_t stream) {
  const float* x    = (const float*)d_in[0];
  const float* inM  = (const float*)d_in[1];
  const float* outM = (const float*)d_in[2];
  const float* W1w  = (const float*)d_in[3];
  const float* b1w  = (const float*)d_in[4];
  const float* W1u  = (const float*)d_in[5];
  const float* b1u  = (const float*)d_in[6];
  const float* W2w  = (const float*)d_in[7];
  const float* b2w  = (const float*)d_in[8];
  const float* W2u  = (const float*)d_in[9];
  const float* b2u  = (const float*)d_in[10];
  const float* W3w  = (const float*)d_in[11];
  const float* b3w  = (const float*)d_in[12];
  const float* W3u  = (const float*)d_in[13];
  const float* b3u  = (const float*)d_in[14];
  float* hout = (float*)d_out;   // h lives in d_out across timesteps

  char* ws = (char*)d_ws;
  __hip_bfloat16* Wzr = (__hip_bfloat16*)ws;                 // 2048*6144*2 = 25,165,824 B
  __hip_bfloat16* Wh  = (__hip_bfloat16*)(ws + 25165824);    // 1024*6144*2 = 12,582,912 B
  const size_t fixed = 37748736;
  // per-batch-element chunk cost: Abuf 80*SA_*2 + zbuf 80*1024*4 = 1,638,400 B
  int Rb = 256;                                              // batch elems per chunk (mult of 8)
  while (Rb > 8 && fixed + (size_t)Rb * 1638400ull > ws_size) Rb -= 8;
  float* zbuf = (float*)(ws + fixed);                        // Rb*80*1024*4
  __hip_bfloat16* Abuf = (__hip_bfloat16*)(ws + fixed + (size_t)Rb * 327680ull);

  pack_weights<<<(3072 * 3072) / 256, 256, 0, stream>>>(
      W1w, W1u, W2w, W2u, W3w, W3u, Wzr, Wh);

  for (int t = 0; t < 3; ++t) {
    const float* hsrc = (t == 0) ? x : (const float*)hout;
    for (int b0 = 0; b0 < B_; b0 += Rb) {
      const int nb = (B_ - b0 < Rb) ? (B_ - b0) : Rb;
      const int rows = N_ * nb;                  // 80*nb, nb mult of 8 -> /160 integral
      const int mtiles = rows / 160;
      const float* hc = hsrc + (size_t)b0 * N_ * D_;
      prop_kernel<<<dim3(nb, D_ / 256), 256, 0, stream>>>(hc, inM, outM, Abuf);
      gemm_kernel<true><<<mtiles * 16, 256, 0, stream>>>(
          Abuf, Wzr, b1w, b1u, b2w, b2u, hc, zbuf, Abuf, nullptr, mtiles);
      gemm_kernel<false><<<mtiles * 8, 256, 0, stream>>>(
          Abuf, Wh, b3w, b3u, nullptr, nullptr, hc, zbuf, nullptr,
          hout + (size_t)b0 * N_ * D_, mtiles);
    }
  }
}